// Round 7
// baseline (2275.359 us; speedup 1.0000x reference)
//
#include <hip/hip_runtime.h>
#include <math.h>

#define NPTS 8192
#define KNNK 10

typedef __attribute__((ext_vector_type(8))) short bf16x8s;
typedef __attribute__((ext_vector_type(4))) float f32x4;

__device__ __forceinline__ float preluf(float v, float a){ return v >= 0.f ? v : a*v; }
__device__ __forceinline__ float4 f4fma(float a, float4 b, float4 c){
  return make_float4(fmaf(a,b.x,c.x), fmaf(a,b.y,c.y), fmaf(a,b.z,c.z), fmaf(a,b.w,c.w));
}

// value-only top-10 (ascending); pure min/max network, full-rate f32.
// Body is a no-op for lanes with d >= bd[9] -> wave-uniform execution safe.
__device__ __forceinline__ void vins10(float* bd, float d){
  if (__any(d < bd[9])){
    float t = d;
    #pragma unroll
    for (int s=0;s<10;++s){
      float mn = fminf(bd[s], t);
      float mx = fmaxf(bd[s], t);
      bd[s] = mn; t = mx;
    }
  }
}

// u64 lex key: (ordered-float-bits(d) << 32) | j ; smaller = better
__device__ __forceinline__ unsigned long long dkey(float d, int j){
  int s = __float_as_int(d);
  unsigned u = (unsigned)s ^ (unsigned)((s>>31) | 0x80000000);
  return ((unsigned long long)u << 32) | (unsigned)j;
}

// split float into bf16 hi/lo (rne); returns packed hi pair, sets lo pair
__device__ __forceinline__ unsigned bfsplit2(float a, float b, unsigned& lo2){
  unsigned ua = __float_as_uint(a), ub = __float_as_uint(b);
  unsigned ha = (ua + 0x7FFFu + ((ua>>16)&1u)) & 0xFFFF0000u;
  unsigned hb = (ub + 0x7FFFu + ((ub>>16)&1u)) & 0xFFFF0000u;
  float ra = a - __uint_as_float(ha);
  float rb = b - __uint_as_float(hb);
  unsigned la = __float_as_uint(ra), lb = __float_as_uint(rb);
  unsigned qa = (la + 0x7FFFu + ((la>>16)&1u)) >> 16;
  unsigned qb = (lb + 0x7FFFu + ((lb>>16)&1u)) & 0xFFFF0000u;
  lo2 = qa | qb;
  return (ha >> 16) | hb;
}

// ---------- prep: x0pad (targets padded to 4ch) + sqnorm ----------
__global__ __launch_bounds__(256) void prep0_kernel(const float* __restrict__ T,
                                                    float* __restrict__ x0,
                                                    float* __restrict__ sqn){
  int p = blockIdx.x*256 + threadIdx.x;
  float t0 = T[p*3+0], t1 = T[p*3+1], t2 = T[p*3+2];
  *(float4*)(x0 + (size_t)p*4) = make_float4(t0,t1,t2,0.f);
  float s = fmaf(t0,t0,0.f); s = fmaf(t1,t1,s); s = fmaf(t2,t2,s); s = fmaf(0.f,0.f,s);
  sqn[p] = s;
}

__global__ __launch_bounds__(256) void sqnorm_kernel(const float* __restrict__ XC, int cin,
                                                     float* __restrict__ sqn){
  int p = blockIdx.x*256 + threadIdx.x;
  const float4* r = (const float4*)(XC + (size_t)p*192 + cin);
  float s = 0.f;
  #pragma unroll
  for (int c4=0;c4<16;++c4){
    float4 v = r[c4];
    s = fmaf(v.x,v.x,s); s = fmaf(v.y,v.y,s); s = fmaf(v.z,v.z,s); s = fmaf(v.w,v.w,s);
  }
  sqn[p] = s;
}

// ---------- KNN C=64: two-pass (pass1 f32 value top-10, pass2 threshold-collect) ----------
__global__ __launch_bounds__(256, 2) void knn64_kernel(const float* __restrict__ X, int ldx, int coff,
                                                       const float* __restrict__ sqn,
                                                       unsigned long long* __restrict__ cbuf,
                                                       int* __restrict__ ccnt){
  __shared__ __align__(16) unsigned short xq[2*128*72];  // [hilo][q][72] bf16 bits
  __shared__ __align__(16) unsigned char uni[36864];     // xj bf16 | dch[128][68] f32 | value lists
  __shared__ float s_x2q[128];
  __shared__ float s_x2j[128];
  __shared__ float sthr[128];
  __shared__ int   scnt[128];

  unsigned short* xj = (unsigned short*)uni;
  float* dch = (float*)uni;
  float* lst = (float*)uni;                  // [128][20] pass-1 value lists

  const int b   = blockIdx.y;
  const int q0  = blockIdx.x * 128;
  const int jh  = blockIdx.z;
  const int tid = threadIdx.x;
  const int L   = tid & 63;
  const int w   = tid >> 6;
  const int lm  = L & 15;
  const int kg  = L >> 4;
  const int tq  = tid & 127;
  const int th  = tid >> 7;

  const float* Xb = X + (size_t)b * NPTS * ldx + coff;

  // stage queries (hi/lo bf16), once (persists across both passes)
  #pragma unroll
  for (int s=0;s<8;++s){
    int e = tid + s*256;
    int r = e >> 4, c4 = (e & 15) << 2;
    float4 v = *(const float4*)(Xb + (size_t)(q0+r)*ldx + c4);
    unsigned lo01, lo23;
    unsigned hi01 = bfsplit2(v.x, v.y, lo01);
    unsigned hi23 = bfsplit2(v.z, v.w, lo23);
    uint2 hp; hp.x = hi01; hp.y = hi23;
    uint2 lp; lp.x = lo01; lp.y = lo23;
    *(uint2*)&xq[r*72 + c4]        = hp;
    *(uint2*)&xq[9216 + r*72 + c4] = lp;
  }
  if (tid < 128) s_x2q[tid] = sqn[b*NPTS + q0 + tid];

  float bd[10];
  #pragma unroll
  for (int u=0;u<10;++u) bd[u] = INFINITY;

  // ================= pass 1: top-10 distance VALUES =================
  for (int t = 0; t < 32; ++t) {
    const int j0 = jh*4096 + t*128;
    #pragma unroll
    for (int s=0;s<8;++s){
      int e = tid + s*256;
      int r = e >> 4, c4 = (e & 15) << 2;
      float4 v = *(const float4*)(Xb + (size_t)(j0+r)*ldx + c4);
      unsigned lo01, lo23;
      unsigned hi01 = bfsplit2(v.x, v.y, lo01);
      unsigned hi23 = bfsplit2(v.z, v.w, lo23);
      uint2 hp; hp.x = hi01; hp.y = hi23;
      uint2 lp; lp.x = lo01; lp.y = lo23;
      *(uint2*)&xj[r*72 + c4]        = hp;
      *(uint2*)&xj[9216 + r*72 + c4] = lp;
    }
    if (tid < 128) s_x2j[tid] = sqn[b*NPTS + j0 + tid];
    __syncthreads();

    f32x4 acc[2][8];
    #pragma unroll
    for (int mt=0;mt<2;++mt)
      #pragma unroll
      for (int nt=0;nt<8;++nt) acc[mt][nt] = (f32x4){0.f,0.f,0.f,0.f};

    #pragma unroll
    for (int kc=0;kc<2;++kc){
      const int ko = kc*32 + kg*8;
      bf16x8s ah[2], al[2];
      #pragma unroll
      for (int mt=0;mt<2;++mt){
        int q = w*32 + mt*16 + lm;
        ah[mt] = *(const bf16x8s*)&xq[q*72 + ko];
        al[mt] = *(const bf16x8s*)&xq[9216 + q*72 + ko];
      }
      #pragma unroll
      for (int nt=0;nt<8;++nt){
        int n = nt*16 + lm;
        bf16x8s bh = *(const bf16x8s*)&xj[n*72 + ko];
        bf16x8s bl = *(const bf16x8s*)&xj[9216 + n*72 + ko];
        #pragma unroll
        for (int mt=0;mt<2;++mt){
          acc[mt][nt] = __builtin_amdgcn_mfma_f32_16x16x32_bf16(ah[mt], bh, acc[mt][nt], 0,0,0);
          acc[mt][nt] = __builtin_amdgcn_mfma_f32_16x16x32_bf16(ah[mt], bl, acc[mt][nt], 0,0,0);
          acc[mt][nt] = __builtin_amdgcn_mfma_f32_16x16x32_bf16(al[mt], bh, acc[mt][nt], 0,0,0);
        }
      }
    }
    __syncthreads();   // xj reads done; uni becomes dch

    #pragma unroll
    for (int h=0; h<2; ++h) {
      #pragma unroll
      for (int mt=0;mt<2;++mt){
        #pragma unroll
        for (int ntl=0;ntl<4;++ntl){
          int nt = h*4 + ntl;
          f32x4 c = acc[mt][nt];
          int colc = ntl*16 + lm;
          float xj2 = s_x2j[h*64 + colc];
          #pragma unroll
          for (int r=0;r<4;++r){
            int qrow = w*32 + mt*16 + kg*4 + r;
            dch[qrow*68 + colc] = s_x2q[qrow] + xj2 - 2.0f*c[r];
          }
        }
      }
      __syncthreads();
      {
        #pragma unroll
        for (int c4=0;c4<8;++c4){
          float4 dv = *(const float4*)&dch[tq*68 + th*32 + c4*4];
          vins10(bd, dv.x);
          vins10(bd, dv.y);
          vins10(bd, dv.z);
          vins10(bd, dv.w);
        }
      }
      __syncthreads();
    }
  }

  // block threshold: 10th smallest value over this block's 4096 candidates
  #pragma unroll
  for (int u=0;u<10;++u) lst[tq*20 + th*10 + u] = bd[u];
  __syncthreads();
  if (tid < 128) {
    int ia=0, ib=0; float v = 0.f;
    #pragma unroll
    for (int u=0;u<10;++u){
      float da = lst[tid*20+ia], db = lst[tid*20+10+ib];
      bool ta = da < db;
      v = ta ? da : db;
      ia += ta ? 1 : 0; ib += ta ? 0 : 1;
    }
    sthr[tid] = v;
    scnt[tid] = 0;
  }
  __syncthreads();
  const float thr = sthr[tq];
  const size_t base16 = ((size_t)jh*(4*NPTS) + (size_t)b*NPTS + q0 + tq)*16;

  // ================= pass 2: recompute + collect (d <= thr) =================
  for (int t = 0; t < 32; ++t) {
    const int j0 = jh*4096 + t*128;
    #pragma unroll
    for (int s=0;s<8;++s){
      int e = tid + s*256;
      int r = e >> 4, c4 = (e & 15) << 2;
      float4 v = *(const float4*)(Xb + (size_t)(j0+r)*ldx + c4);
      unsigned lo01, lo23;
      unsigned hi01 = bfsplit2(v.x, v.y, lo01);
      unsigned hi23 = bfsplit2(v.z, v.w, lo23);
      uint2 hp; hp.x = hi01; hp.y = hi23;
      uint2 lp; lp.x = lo01; lp.y = lo23;
      *(uint2*)&xj[r*72 + c4]        = hp;
      *(uint2*)&xj[9216 + r*72 + c4] = lp;
    }
    if (tid < 128) s_x2j[tid] = sqn[b*NPTS + j0 + tid];
    __syncthreads();

    f32x4 acc[2][8];
    #pragma unroll
    for (int mt=0;mt<2;++mt)
      #pragma unroll
      for (int nt=0;nt<8;++nt) acc[mt][nt] = (f32x4){0.f,0.f,0.f,0.f};

    #pragma unroll
    for (int kc=0;kc<2;++kc){
      const int ko = kc*32 + kg*8;
      bf16x8s ah[2], al[2];
      #pragma unroll
      for (int mt=0;mt<2;++mt){
        int q = w*32 + mt*16 + lm;
        ah[mt] = *(const bf16x8s*)&xq[q*72 + ko];
        al[mt] = *(const bf16x8s*)&xq[9216 + q*72 + ko];
      }
      #pragma unroll
      for (int nt=0;nt<8;++nt){
        int n = nt*16 + lm;
        bf16x8s bh = *(const bf16x8s*)&xj[n*72 + ko];
        bf16x8s bl = *(const bf16x8s*)&xj[9216 + n*72 + ko];
        #pragma unroll
        for (int mt=0;mt<2;++mt){
          acc[mt][nt] = __builtin_amdgcn_mfma_f32_16x16x32_bf16(ah[mt], bh, acc[mt][nt], 0,0,0);
          acc[mt][nt] = __builtin_amdgcn_mfma_f32_16x16x32_bf16(ah[mt], bl, acc[mt][nt], 0,0,0);
          acc[mt][nt] = __builtin_amdgcn_mfma_f32_16x16x32_bf16(al[mt], bh, acc[mt][nt], 0,0,0);
        }
      }
    }
    __syncthreads();

    #pragma unroll
    for (int h=0; h<2; ++h) {
      #pragma unroll
      for (int mt=0;mt<2;++mt){
        #pragma unroll
        for (int ntl=0;ntl<4;++ntl){
          int nt = h*4 + ntl;
          f32x4 c = acc[mt][nt];
          int colc = ntl*16 + lm;
          float xj2 = s_x2j[h*64 + colc];
          #pragma unroll
          for (int r=0;r<4;++r){
            int qrow = w*32 + mt*16 + kg*4 + r;
            dch[qrow*68 + colc] = s_x2q[qrow] + xj2 - 2.0f*c[r];
          }
        }
      }
      __syncthreads();
      {
        const int jb0 = j0 + h*64 + th*32;
        #pragma unroll
        for (int c4=0;c4<8;++c4){
          float4 dv = *(const float4*)&dch[tq*68 + th*32 + c4*4];
          int jj = jb0 + c4*4;
          float dd[4] = {dv.x, dv.y, dv.z, dv.w};
          #pragma unroll
          for (int u=0;u<4;++u){
            if (dd[u] <= thr){
              int slot = atomicAdd(&scnt[tq], 1);
              if (slot < 16) cbuf[base16 + slot] = dkey(dd[u], jj+u);
            }
          }
        }
      }
      __syncthreads();
    }
  }

  if (tid < 128) ccnt[jh*(4*NPTS) + b*NPTS + q0 + tid] = scnt[tid];
}

// ---------- KNN for conv1 (C=4, fp32 VALU GEMM): same two-pass structure ----------
__global__ __launch_bounds__(256, 2) void knn4_kernel(const float* __restrict__ X,
                                                      const float* __restrict__ sqn,
                                                      unsigned long long* __restrict__ cbuf,
                                                      int* __restrict__ ccnt){
  __shared__ __align__(16) float xqT[4*132];
  __shared__ __align__(16) float uni[8704];    // xjT[4][132] | dch[128][68] | value lists
  __shared__ float s_x2q[128];
  __shared__ float s_x2j[128];
  __shared__ float sthr[128];
  __shared__ int   scnt[128];

  const int b   = blockIdx.y;
  const int q0  = blockIdx.x * 128;
  const int jh  = blockIdx.z;
  const int tid = threadIdx.x;
  const int tn  = tid & 15;
  const int tm  = tid >> 4;
  const int tq  = tid & 127;
  const int th  = tid >> 7;

  const float* Xb = X + (size_t)b * NPTS * 4;

  for (int i = tid; i < 128; i += 256) {
    float4 v = *(const float4*)(Xb + (size_t)(q0+i)*4);
    xqT[0*132+i] = v.x; xqT[1*132+i] = v.y; xqT[2*132+i] = v.z; xqT[3*132+i] = v.w;
  }
  if (tid < 128) s_x2q[tid] = sqn[b*NPTS + q0 + tid];

  const int sw  = ((tn>>2)&3) << 2;
  const int bp0 = (tn*8)     ^ sw;
  const int bp1 = (tn*8 + 4) ^ sw;

  float bd[10];
  #pragma unroll
  for (int u=0;u<10;++u) bd[u] = INFINITY;

  // ---- pass 1 ----
  for (int t = 0; t < 32; ++t) {
    const int j0 = jh*4096 + t*128;
    __syncthreads();
    for (int i = tid; i < 128; i += 256) {
      float4 v = *(const float4*)(Xb + (size_t)(j0+i)*4);
      int pj = i ^ (((i>>5)&3) << 2);
      uni[0*132+pj] = v.x; uni[1*132+pj] = v.y; uni[2*132+pj] = v.z; uni[3*132+pj] = v.w;
    }
    if (tid < 128) s_x2j[tid] = sqn[b*NPTS + j0 + tid];
    __syncthreads();

    float acc[8][8];
    #pragma unroll
    for (int i=0;i<8;++i)
      #pragma unroll
      for (int j=0;j<8;++j) acc[i][j] = 0.f;

    #pragma unroll
    for (int kk=0; kk<4; ++kk) {
      float av[8], bv[8];
      *(float4*)&av[0] = *(const float4*)&xqT[kk*132 + tm*8];
      *(float4*)&av[4] = *(const float4*)&xqT[kk*132 + tm*8 + 4];
      *(float4*)&bv[0] = *(const float4*)&uni[kk*132 + bp0];
      *(float4*)&bv[4] = *(const float4*)&uni[kk*132 + bp1];
      #pragma unroll
      for (int i=0;i<8;++i)
        #pragma unroll
        for (int j=0;j<8;++j)
          acc[i][j] = fmaf(av[i], bv[j], acc[i][j]);
    }
    __syncthreads();

    #pragma unroll
    for (int h=0; h<2; ++h) {
      if ((tn>>3) == h) {
        #pragma unroll
        for (int qi=0; qi<8; ++qi) {
          const int row = tm*8 + qi;
          const float xq2 = s_x2q[row];
          float vv[8];
          #pragma unroll
          for (int u=0;u<8;++u)
            vv[u] = xq2 + s_x2j[tn*8 + u] - 2.f*acc[qi][u];
          *(float4*)&uni[row*68 + (tn&7)*8]     = make_float4(vv[0],vv[1],vv[2],vv[3]);
          *(float4*)&uni[row*68 + (tn&7)*8 + 4] = make_float4(vv[4],vv[5],vv[6],vv[7]);
        }
      }
      __syncthreads();
      {
        #pragma unroll
        for (int c4=0;c4<8;++c4){
          float4 dv = *(const float4*)&uni[tq*68 + th*32 + c4*4];
          vins10(bd, dv.x);
          vins10(bd, dv.y);
          vins10(bd, dv.z);
          vins10(bd, dv.w);
        }
      }
      __syncthreads();
    }
  }

  // block threshold
  float* lst = uni;   // [128][20]
  #pragma unroll
  for (int u=0;u<10;++u) lst[tq*20 + th*10 + u] = bd[u];
  __syncthreads();
  if (tid < 128) {
    int ia=0, ib=0; float v = 0.f;
    #pragma unroll
    for (int u=0;u<10;++u){
      float da = lst[tid*20+ia], db = lst[tid*20+10+ib];
      bool ta = da < db;
      v = ta ? da : db;
      ia += ta ? 1 : 0; ib += ta ? 0 : 1;
    }
    sthr[tid] = v;
    scnt[tid] = 0;
  }
  __syncthreads();
  const float thr = sthr[tq];
  const size_t base16 = ((size_t)jh*(4*NPTS) + (size_t)b*NPTS + q0 + tq)*16;

  // ---- pass 2 ----
  for (int t = 0; t < 32; ++t) {
    const int j0 = jh*4096 + t*128;
    __syncthreads();
    for (int i = tid; i < 128; i += 256) {
      float4 v = *(const float4*)(Xb + (size_t)(j0+i)*4);
      int pj = i ^ (((i>>5)&3) << 2);
      uni[0*132+pj] = v.x; uni[1*132+pj] = v.y; uni[2*132+pj] = v.z; uni[3*132+pj] = v.w;
    }
    if (tid < 128) s_x2j[tid] = sqn[b*NPTS + j0 + tid];
    __syncthreads();

    float acc[8][8];
    #pragma unroll
    for (int i=0;i<8;++i)
      #pragma unroll
      for (int j=0;j<8;++j) acc[i][j] = 0.f;

    #pragma unroll
    for (int kk=0; kk<4; ++kk) {
      float av[8], bv[8];
      *(float4*)&av[0] = *(const float4*)&xqT[kk*132 + tm*8];
      *(float4*)&av[4] = *(const float4*)&xqT[kk*132 + tm*8 + 4];
      *(float4*)&bv[0] = *(const float4*)&uni[kk*132 + bp0];
      *(float4*)&bv[4] = *(const float4*)&uni[kk*132 + bp1];
      #pragma unroll
      for (int i=0;i<8;++i)
        #pragma unroll
        for (int j=0;j<8;++j)
          acc[i][j] = fmaf(av[i], bv[j], acc[i][j]);
    }
    __syncthreads();

    #pragma unroll
    for (int h=0; h<2; ++h) {
      if ((tn>>3) == h) {
        #pragma unroll
        for (int qi=0; qi<8; ++qi) {
          const int row = tm*8 + qi;
          const float xq2 = s_x2q[row];
          float vv[8];
          #pragma unroll
          for (int u=0;u<8;++u)
            vv[u] = xq2 + s_x2j[tn*8 + u] - 2.f*acc[qi][u];
          *(float4*)&uni[row*68 + (tn&7)*8]     = make_float4(vv[0],vv[1],vv[2],vv[3]);
          *(float4*)&uni[row*68 + (tn&7)*8 + 4] = make_float4(vv[4],vv[5],vv[6],vv[7]);
        }
      }
      __syncthreads();
      {
        const int jb0 = j0 + h*64 + th*32;
        #pragma unroll
        for (int c4=0;c4<8;++c4){
          float4 dv = *(const float4*)&uni[tq*68 + th*32 + c4*4];
          int jj = jb0 + c4*4;
          float dd[4] = {dv.x, dv.y, dv.z, dv.w};
          #pragma unroll
          for (int u=0;u<4;++u){
            if (dd[u] <= thr){
              int slot = atomicAdd(&scnt[tq], 1);
              if (slot < 16) cbuf[base16 + slot] = dkey(dd[u], jj+u);
            }
          }
        }
      }
      __syncthreads();
    }
  }

  if (tid < 128) ccnt[jh*(4*NPTS) + b*NPTS + q0 + tid] = scnt[tid];
}

// ---------- finalize: lex top-10 over the two jh-halves' collected entries ----------
__global__ __launch_bounds__(256) void knnfin_kernel(const unsigned long long* __restrict__ cbuf,
                                                     const int* __restrict__ ccnt,
                                                     int* __restrict__ idxout){
  int p = blockIdx.x*256 + threadIdx.x;   // 0..32767
  unsigned long long bk[10];
  #pragma unroll
  for (int u=0;u<10;++u) bk[u] = ~0ULL;
  #pragma unroll
  for (int hf=0; hf<2; ++hf){
    int c = ccnt[hf*(4*NPTS) + p];
    c = c < 16 ? c : 16;
    const unsigned long long* src = cbuf + ((size_t)hf*(4*NPTS) + p)*16;
    for (int i=0;i<c;++i){
      unsigned long long t = src[i];
      #pragma unroll
      for (int s=0;s<10;++s){
        bool lt = t < bk[s];
        unsigned long long mn = lt ? t : bk[s];
        unsigned long long mx = lt ? bk[s] : t;
        bk[s] = mn; t = mx;
      }
    }
  }
  int* op = idxout + (size_t)p*10;
  #pragma unroll
  for (int u=0;u<10;++u) op[u] = (int)(bk[u] & 8191ULL);
}

// ---------- prep U/D for 64-ch edge conv ----------
__global__ __launch_bounds__(256) void prepUD64_kernel(const float* __restrict__ XC, int cin,
                                                       const float* __restrict__ W,
                                                       float* __restrict__ U,
                                                       float* __restrict__ D){
  int p = blockIdx.x*256 + threadIdx.x;
  float x[64];
  {
    const float4* xr = (const float4*)(XC + (size_t)p*192 + cin);
    #pragma unroll
    for (int c4=0;c4<16;++c4){
      float4 v = xr[c4];
      x[c4*4]=v.x; x[c4*4+1]=v.y; x[c4*4+2]=v.z; x[c4*4+3]=v.w;
    }
  }
  const float4* W4 = (const float4*)W;
  float4 z[16];
  #pragma unroll
  for (int o=0;o<16;++o) z[o] = make_float4(0,0,0,0);
  #pragma unroll
  for (int c=0;c<64;++c) {
    const float xc = x[c];
    #pragma unroll
    for (int o=0;o<16;++o) z[o] = f4fma(xc, W4[c*16+o], z[o]);
  }
  float4* up = (float4*)(U + (size_t)p*64);
  #pragma unroll
  for (int o=0;o<16;++o) up[o] = z[o];
  #pragma unroll
  for (int o=0;o<16;++o) z[o] = make_float4(0,0,0,0);
  #pragma unroll
  for (int c=0;c<64;++c) {
    const float xc = x[c];
    #pragma unroll
    for (int o=0;o<16;++o) {
      float4 wt = W4[c*16+o], wb = W4[(64+c)*16+o];
      float4 wd = make_float4(wb.x-wt.x, wb.y-wt.y, wb.z-wt.z, wb.w-wt.w);
      z[o] = f4fma(xc, wd, z[o]);
    }
  }
  float4* dp = (float4*)(D + (size_t)p*64);
  #pragma unroll
  for (int o=0;o<16;++o) dp[o] = z[o];
}

// ---------- prep U/D for conv1 ----------
__global__ __launch_bounds__(256) void prepUD12_kernel(const float* __restrict__ T,
                                                       const float* __restrict__ W1,
                                                       float* __restrict__ U,
                                                       float* __restrict__ D){
  int p = blockIdx.x*256 + threadIdx.x;
  float t[3] = {T[p*3+0], T[p*3+1], T[p*3+2]};
  const float4* W = (const float4*)W1;
  float4 u[16], q[16];
  #pragma unroll
  for (int o=0;o<16;++o){ u[o]=make_float4(0,0,0,0); q[o]=make_float4(0,0,0,0); }
  #pragma unroll
  for (int c=0;c<3;++c){
    const float tc = t[c];
    #pragma unroll
    for (int o=0;o<16;++o){
      float4 ws  = W[c*16+o],     ws2 = W[(c+3)*16+o];
      float4 wq  = W[(c+6)*16+o], wq2 = W[(c+9)*16+o];
      u[o] = f4fma(tc, make_float4(ws.x+ws2.x, ws.y+ws2.y, ws.z+ws2.z, ws.w+ws2.w), u[o]);
      q[o] = f4fma(tc, make_float4(wq.x+wq2.x, wq.y+wq2.y, wq.z+wq2.z, wq.w+wq2.w), q[o]);
    }
  }
  float4* up = (float4*)(U + (size_t)p*64);
  float4* dp = (float4*)(D + (size_t)p*64);
  #pragma unroll
  for (int o=0;o<16;++o){
    up[o] = u[o];
    dp[o] = make_float4(q[o].x-u[o].x, q[o].y-u[o].y, q[o].z-u[o].z, q[o].w-u[o].w);
  }
}

// ---------- two-layer edge conv, wave-per-point: lane = out-channel ----------
__global__ __launch_bounds__(256) void edge2w_kernel(const float* __restrict__ U,
                                                     const float* __restrict__ Dp,
                                                     const int* __restrict__ idx,
                                                     const float* __restrict__ Wb,
                                                     const float* __restrict__ PA, int paa, int pab,
                                                     float* __restrict__ out, int coff){
  __shared__ __align__(16) float sh[4][10][68];
  const int tid = threadIdx.x;
  const int w = tid >> 6, o = tid & 63;
  const int p = blockIdx.x*4 + w, b = p >> 13;
  const float aa = PA[paa], ab = PA[pab];

  float wreg[64];
  #pragma unroll
  for (int c=0;c<64;++c) wreg[c] = Wb[c*64 + o];

  const float dc = Dp[(size_t)p*64 + o];

  #pragma unroll
  for (int k=0;k<10;++k){
    int nb = idx[p*10 + k];
    float u = U[((size_t)(b<<13)+nb)*64 + o];
    sh[w][k][o] = preluf(u + dc, aa);
  }
  __syncthreads();

  float mx = -INFINITY;
  #pragma unroll 2
  for (int k=0;k<10;++k){
    float a0=0.f,a1=0.f,a2=0.f,a3=0.f;
    #pragma unroll
    for (int c4=0;c4<16;++c4){
      float4 hv = *(const float4*)&sh[w][k][c4*4];
      a0 = fmaf(hv.x, wreg[c4*4+0], a0);
      a1 = fmaf(hv.y, wreg[c4*4+1], a1);
      a2 = fmaf(hv.z, wreg[c4*4+2], a2);
      a3 = fmaf(hv.w, wreg[c4*4+3], a3);
    }
    float z = (a0+a1)+(a2+a3);
    mx = fmaxf(mx, preluf(z, ab));
  }
  out[(size_t)p*192 + coff + o] = mx;
}

// ---------- single-layer edge conv (conv3), wave-per-point ----------
__global__ __launch_bounds__(256) void edge1w_kernel(const float* __restrict__ U,
                                                     const float* __restrict__ Dp,
                                                     const int* __restrict__ idx,
                                                     const float* __restrict__ PA, int paa,
                                                     float* __restrict__ out, int coff){
  const int tid = threadIdx.x;
  const int w = tid >> 6, o = tid & 63;
  const int p = blockIdx.x*4 + w, b = p >> 13;
  const float aa = PA[paa];
  const float dc = Dp[(size_t)p*64 + o];
  float mx = -INFINITY;
  #pragma unroll
  for (int k=0;k<10;++k){
    int nb = idx[p*10 + k];
    float u = U[((size_t)(b<<13)+nb)*64 + o];
    mx = fmaxf(mx, preluf(u + dc, aa));
  }
  out[(size_t)p*192 + coff + o] = mx;
}

// ---------- weight prep: W[K][N] fp32 -> Wh/Wl[N][K] bf16 bits (transposed hi/lo) ----------
__global__ __launch_bounds__(256) void prepW_kernel(const float* __restrict__ W, int K, int N,
                                                    unsigned short* __restrict__ Wh,
                                                    unsigned short* __restrict__ Wl){
  int k = blockIdx.x;
  for (int n = threadIdx.x; n < N; n += 256){
    float v = W[(size_t)k*N + n];
    unsigned ua = __float_as_uint(v);
    unsigned h = (ua + 0x7FFFu + ((ua>>16)&1u)) & 0xFFFF0000u;
    float r = v - __uint_as_float(h);
    unsigned ub = __float_as_uint(r);
    unsigned l = (ub + 0x7FFFu + ((ub>>16)&1u)) >> 16;
    Wh[(size_t)n*K + k] = (unsigned short)(h >> 16);
    Wl[(size_t)n*K + k] = (unsigned short)l;
  }
}

// ---------- MFMA bf16 hi/lo GEMM: C = prelu(A@W [+bias]); EPI2: colmax partials ----------
template<int EPI>
__global__ __launch_bounds__(256, 2) void mgemm_kernel(const float* __restrict__ A, int lda,
                                                       const unsigned short* __restrict__ WhT,
                                                       const unsigned short* __restrict__ WlT,
                                                       int K,
                                                       float* __restrict__ C, int ldc,
                                                       const float* __restrict__ bias,
                                                       const float* __restrict__ PA, int pidx,
                                                       int Ntot){
  __shared__ __align__(16) unsigned char smem[73728];
  unsigned short* sa = (unsigned short*)smem;
  unsigned short* sb = (unsigned short*)(smem + 36864);
  float* cst = (float*)smem;

  const int tid = threadIdx.x;
  const int m0 = blockIdx.x*128, n0 = blockIdx.y*128;
  const int L = tid & 63, w = tid >> 6;
  const int lm = L & 15, kg = L >> 4;

  f32x4 acc[2][8];
  #pragma unroll
  for (int mt=0;mt<2;++mt)
    #pragma unroll
    for (int nt=0;nt<8;++nt) acc[mt][nt] = (f32x4){0.f,0.f,0.f,0.f};

  for (int c0 = 0; c0 < K; c0 += 64) {
    __syncthreads();
    #pragma unroll
    for (int s=0;s<8;++s){
      int e = tid + s*256;
      int r = e >> 4, kq = (e & 15) << 2;
      float4 v = *(const float4*)(A + (size_t)(m0+r)*lda + c0 + kq);
      unsigned lo01, lo23;
      unsigned hi01 = bfsplit2(v.x, v.y, lo01);
      unsigned hi23 = bfsplit2(v.z, v.w, lo23);
      uint2 hp; hp.x = hi01; hp.y = hi23;
      uint2 lp; lp.x = lo01; lp.y = lo23;
      *(uint2*)&sa[r*72 + kq]        = hp;
      *(uint2*)&sa[9216 + r*72 + kq] = lp;
    }
    #pragma unroll
    for (int s=0;s<4;++s){
      int e = tid + s*256;
      int col = e >> 3, ko = (e & 7) << 3;
      *(uint4*)&sb[col*72 + ko]        = *(const uint4*)&WhT[(size_t)(n0+col)*K + c0 + ko];
      *(uint4*)&sb[9216 + col*72 + ko] = *(const uint4*)&WlT[(size_t)(n0+col)*K + c0 + ko];
    }
    __syncthreads();

    #pragma unroll
    for (int kc=0;kc<2;++kc){
      const int ko = kc*32 + kg*8;
      bf16x8s ah[2], al[2];
      #pragma unroll
      for (int mt=0;mt<2;++mt){
        int q = w*32 + mt*16 + lm;
        ah[mt] = *(const bf16x8s*)&sa[q*72 + ko];
        al[mt] = *(const bf16x8s*)&sa[9216 + q*72 + ko];
      }
      #pragma unroll
      for (int nt=0;nt<8;++nt){
        int n = nt*16 + lm;
        bf16x8s bh = *(const bf16x8s*)&sb[n*72 + ko];
        bf16x8s bl = *(const bf16x8s*)&sb[9216 + n*72 + ko];
        #pragma unroll
        for (int mt=0;mt<2;++mt){
          acc[mt][nt] = __builtin_amdgcn_mfma_f32_16x16x32_bf16(ah[mt], bh, acc[mt][nt], 0,0,0);
          acc[mt][nt] = __builtin_amdgcn_mfma_f32_16x16x32_bf16(ah[mt], bl, acc[mt][nt], 0,0,0);
          acc[mt][nt] = __builtin_amdgcn_mfma_f32_16x16x32_bf16(al[mt], bh, acc[mt][nt], 0,0,0);
        }
      }
    }
  }
  __syncthreads();

  const float a = PA[pidx];
  if (EPI == 2) {
    #pragma unroll
    for (int nt=0;nt<8;++nt){
      f32x4 c0v = acc[0][nt], c1v = acc[1][nt];
      float m = -INFINITY;
      #pragma unroll
      for (int r=0;r<4;++r){ m = fmaxf(m, preluf(c0v[r], a)); m = fmaxf(m, preluf(c1v[r], a)); }
      m = fmaxf(m, __shfl_xor(m, 16));
      m = fmaxf(m, __shfl_xor(m, 32));
      if (kg == 0) cst[w*128 + nt*16 + lm] = m;
    }
    __syncthreads();
    if (tid < 128){
      float m = fmaxf(fmaxf(cst[tid], cst[128+tid]), fmaxf(cst[256+tid], cst[384+tid]));
      C[(size_t)blockIdx.x*Ntot + n0 + tid] = m;
    }
  } else {
    float bc[8];
    if (EPI == 1){
      int bb = m0 >> 13;
      #pragma unroll
      for (int nt=0;nt<8;++nt) bc[nt] = bias[bb*256 + n0 + nt*16 + lm];
    }
    #pragma unroll
    for (int mt=0;mt<2;++mt){
      #pragma unroll
      for (int nt=0;nt<8;++nt){
        f32x4 c = acc[mt][nt];
        int col = nt*16 + lm;
        #pragma unroll
        for (int r=0;r<4;++r){
          int row = w*32 + mt*16 + kg*4 + r;
          float v = c[r] + (EPI==1 ? bc[nt] : 0.f);
          cst[row*132 + col] = preluf(v, a);
        }
      }
    }
    __syncthreads();
    const int tm = tid & 15, tn = tid >> 4;
    #pragma unroll
    for (int i=0;i<8;++i){
      int row = tm*8 + i;
      float4 v0 = *(const float4*)&cst[row*132 + tn*8];
      float4 v1 = *(const float4*)&cst[row*132 + tn*8 + 4];
      float* cp = C + (size_t)(m0 + row)*ldc + n0 + tn*8;
      *(float4*)cp     = v0;
      *(float4*)(cp+4) = v1;
    }
  }
}

__global__ __launch_bounds__(256) void reduce_pmax(const float* __restrict__ pmax,
                                                   float* __restrict__ x5m){
  int t = blockIdx.x*256 + threadIdx.x;
  if (t < 4096) {
    int b = t >> 10, o = t & 1023;
    float m = -INFINITY;
    for (int mt=0; mt<64; ++mt) m = fmaxf(m, pmax[((size_t)(b*64+mt))*1024 + o]);
    x5m[t] = m;
  }
}

__global__ __launch_bounds__(256) void bias7_kernel(const float* __restrict__ x5m,
                                                    const float* __restrict__ W7,
                                                    float* __restrict__ b7){
  int b = blockIdx.x; int o = threadIdx.x;
  float s = 0.f;
  for (int j=0;j<1024;++j) s = fmaf(x5m[b*1024+j], W7[(size_t)(192+j)*256 + o], s);
  b7[b*256+o] = s;
}

__global__ __launch_bounds__(256) void final10_kernel(const float* __restrict__ y3,
                                                      const float* __restrict__ W10,
                                                      const float* __restrict__ PA,
                                                      float* __restrict__ out){
  int p = blockIdx.x*256 + threadIdx.x;
  const float4* r = (const float4*)(y3 + (size_t)p*128);
  float s0=0.f, s1=0.f;
  #pragma unroll
  for (int c4=0;c4<32;++c4){
    float4 v = r[c4];
    s0 = fmaf(v.x, W10[(c4*4+0)*2+0], s0); s1 = fmaf(v.x, W10[(c4*4+0)*2+1], s1);
    s0 = fmaf(v.y, W10[(c4*4+1)*2+0], s0); s1 = fmaf(v.y, W10[(c4*4+1)*2+1], s1);
    s0 = fmaf(v.z, W10[(c4*4+2)*2+0], s0); s1 = fmaf(v.z, W10[(c4*4+2)*2+1], s1);
    s0 = fmaf(v.w, W10[(c4*4+3)*2+0], s0); s1 = fmaf(v.w, W10[(c4*4+3)*2+1], s1);
  }
  float a = PA[9];
  out[p*2+0] = s0>=0.f? s0 : a*s0;
  out[p*2+1] = s1>=0.f? s1 : a*s1;
}

extern "C" void kernel_launch(void* const* d_in, const int* in_sizes, int n_in,
                              void* d_out, int out_size, void* d_ws, size_t ws_size,
                              hipStream_t stream) {
  const float* T   = (const float*)d_in[0];
  const float* W1  = (const float*)d_in[1];
  const float* W2  = (const float*)d_in[2];
  const float* W3  = (const float*)d_in[3];
  const float* W4  = (const float*)d_in[4];
  const float* W5  = (const float*)d_in[5];
  const float* W6  = (const float*)d_in[6];
  const float* W7  = (const float*)d_in[7];
  const float* W8  = (const float*)d_in[8];
  const float* W9  = (const float*)d_in[9];
  const float* W10 = (const float*)d_in[10];
  const float* PA  = (const float*)d_in[11];

  float* ws   = (float*)d_ws;
  float* x0   = ws + 0;                // 131072
  float* sqn0 = ws + 131072;           // 32768
  float* sqn1 = ws + 163840;           // 32768
  float* sqn2 = ws + 196608;           // 32768
  int*   idx0 = (int*)(ws + 229376);   // 327680
  int*   idx1 = (int*)(ws + 557056);   // 327680
  int*   idx2 = (int*)(ws + 884736);   // 327680
  float* xcat = ws + 1212416;          // 6291456  [B,N,192]
  float* pmax = ws + 7503872;          // 262144 (aliased: ccnt during knn)
  float* x5m  = ws + 7766016;          // 4096
  float* b7   = ws + 7770112;          // 1024
  float* y1   = ws + 7771136;          // 8388608  (aliased: U)
  float* y2   = ws + 16159744;         // 8388608  (aliased: D / knn collect buf)
  float* y3   = xcat;
  float* U    = y1;
  float* D    = y2;
  unsigned long long* cbuf = (unsigned long long*)y2;  // [2][32768][16] u64 = 8 MB
  int* ccnt = (int*)pmax;                              // [2][32768] = 256 KB

  // split/transposed weights: reuse idx region (dead after edge1w)
  unsigned short* wsc = (unsigned short*)(ws + 229376);
  unsigned short* Wh6 = wsc;
  unsigned short* Wl6 = wsc + 196608;
  unsigned short* Wh7 = wsc + 393216;
  unsigned short* Wl7 = wsc + 442368;
  unsigned short* Wh8 = wsc + 491520;
  unsigned short* Wl8 = wsc + 557056;
  unsigned short* Wh9 = wsc + 622592;
  unsigned short* Wl9 = wsc + 655360;

  // conv1
  prep0_kernel<<<128, 256, 0, stream>>>(T, x0, sqn0);
  knn4_kernel<<<dim3(64,4,2), 256, 0, stream>>>(x0, sqn0, cbuf, ccnt);
  knnfin_kernel<<<128, 256, 0, stream>>>(cbuf, ccnt, idx0);
  prepUD12_kernel<<<128, 256, 0, stream>>>(T, W1, U, D);
  edge2w_kernel<<<8192, 256, 0, stream>>>(U, D, idx0, W2, PA, 0, 1, xcat, 0);

  // conv2
  sqnorm_kernel<<<128, 256, 0, stream>>>(xcat, 0, sqn1);
  knn64_kernel<<<dim3(64,4,2), 256, 0, stream>>>(xcat, 192, 0, sqn1, cbuf, ccnt);
  knnfin_kernel<<<128, 256, 0, stream>>>(cbuf, ccnt, idx1);
  prepUD64_kernel<<<128, 256, 0, stream>>>(xcat, 0, W3, U, D);
  edge2w_kernel<<<8192, 256, 0, stream>>>(U, D, idx1, W4, PA, 2, 3, xcat, 64);

  // conv3
  sqnorm_kernel<<<128, 256, 0, stream>>>(xcat, 64, sqn2);
  knn64_kernel<<<dim3(64,4,2), 256, 0, stream>>>(xcat, 192, 64, sqn2, cbuf, ccnt);
  knnfin_kernel<<<128, 256, 0, stream>>>(cbuf, ccnt, idx2);
  prepUD64_kernel<<<128, 256, 0, stream>>>(xcat, 64, W5, U, D);
  edge1w_kernel<<<8192, 256, 0, stream>>>(U, D, idx2, PA, 4, xcat, 128);

  // head weights -> bf16 hi/lo transposed
  prepW_kernel<<<192, 256, 0, stream>>>(W6, 192, 1024, Wh6, Wl6);
  prepW_kernel<<<192, 256, 0, stream>>>(W7, 192, 256,  Wh7, Wl7);
  prepW_kernel<<<256, 256, 0, stream>>>(W8, 256, 256,  Wh8, Wl8);
  prepW_kernel<<<256, 256, 0, stream>>>(W9, 256, 128,  Wh9, Wl9);

  // head
  mgemm_kernel<2><<<dim3(256,8), 256, 0, stream>>>(xcat, 192, Wh6, Wl6, 192, pmax, 0, nullptr, PA, 5, 1024);
  reduce_pmax<<<16, 256, 0, stream>>>(pmax, x5m);
  bias7_kernel<<<4, 256, 0, stream>>>(x5m, W7, b7);
  mgemm_kernel<1><<<dim3(256,2), 256, 0, stream>>>(xcat, 192, Wh7, Wl7, 192, y1, 256, b7, PA, 6, 0);
  mgemm_kernel<0><<<dim3(256,2), 256, 0, stream>>>(y1, 256, Wh8, Wl8, 256, y2, 256, nullptr, PA, 7, 0);
  mgemm_kernel<0><<<dim3(256,1), 256, 0, stream>>>(y2, 256, Wh9, Wl9, 256, y3, 128, nullptr, PA, 8, 0);
  final10_kernel<<<128, 256, 0, stream>>>(y3, W10, PA, (float*)d_out);
}

// Round 9
// 1712.481 us; speedup vs baseline: 1.3287x; 1.3287x over previous
//
#include <hip/hip_runtime.h>
#include <math.h>

#define NPTS 8192
#define KNNK 10

typedef __attribute__((ext_vector_type(8))) short bf16x8s;
typedef __attribute__((ext_vector_type(4))) float f32x4;

__device__ __forceinline__ float preluf(float v, float a){ return v >= 0.f ? v : a*v; }
__device__ __forceinline__ float4 f4fma(float a, float4 b, float4 c){
  return make_float4(fmaf(a,b.x,c.x), fmaf(a,b.y,c.y), fmaf(a,b.z,c.z), fmaf(a,b.w,c.w));
}

// f64 lex key: double(d) with j OR'd into the 29 zero low-mantissa bits.
// Gate g9 = min(own 10th, partner 10th at last exchange): a dropped candidate
// has >=10 strictly-smaller-distance entries already held for this query.
__device__ __forceinline__ void kinsd2(double* bk, float& g9, float pbd9, float d, int j){
  if (__any(d < g9)) {
    double t = (double)d;
    t = __longlong_as_double(__double_as_longlong(t) | (unsigned long long)(unsigned)j);
    #pragma unroll
    for (int s=0;s<10;++s){
      double mn = fmin(bk[s], t);
      double mx = fmax(bk[s], t);
      bk[s] = mn; t = mx;
    }
    g9 = fminf((float)bk[9], pbd9);   // (float)bk[9] rounds back to exact d9
  }
}

// split float into bf16 hi/lo (rne); returns packed hi pair, sets lo pair
__device__ __forceinline__ unsigned bfsplit2(float a, float b, unsigned& lo2){
  unsigned ua = __float_as_uint(a), ub = __float_as_uint(b);
  unsigned ha = (ua + 0x7FFFu + ((ua>>16)&1u)) & 0xFFFF0000u;
  unsigned hb = (ub + 0x7FFFu + ((ub>>16)&1u)) & 0xFFFF0000u;
  float ra = a - __uint_as_float(ha);
  float rb = b - __uint_as_float(hb);
  unsigned la = __float_as_uint(ra), lb = __float_as_uint(rb);
  unsigned qa = (la + 0x7FFFu + ((la>>16)&1u)) >> 16;
  unsigned qb = (lb + 0x7FFFu + ((lb>>16)&1u)) & 0xFFFF0000u;
  lo2 = qa | qb;
  return (ha >> 16) | hb;
}

// ---------- prep: x0pad (targets padded to 4ch) + sqnorm ----------
__global__ __launch_bounds__(256) void prep0_kernel(const float* __restrict__ T,
                                                    float* __restrict__ x0,
                                                    float* __restrict__ sqn){
  int p = blockIdx.x*256 + threadIdx.x;
  float t0 = T[p*3+0], t1 = T[p*3+1], t2 = T[p*3+2];
  *(float4*)(x0 + (size_t)p*4) = make_float4(t0,t1,t2,0.f);
  float s = fmaf(t0,t0,0.f); s = fmaf(t1,t1,s); s = fmaf(t2,t2,s); s = fmaf(0.f,0.f,s);
  sqn[p] = s;
}

// ---------- KNN C=64: MFMA bf16 hi/lo GEMM + f64-key top-10, shared threshold ----------
// R6-proven chunked epilogue: dch[128][68], two 64-col chunks per 128-j tile.
__global__ __launch_bounds__(256, 2) void knn64_kernel(const float* __restrict__ X, int ldx, int coff,
                                                       const float* __restrict__ sqn,
                                                       double* __restrict__ pk){
  __shared__ __align__(16) unsigned short xq[2*128*72];  // 36864 B
  __shared__ __align__(16) unsigned char uni[36864];     // xj bf16 | dch[128][68] f32 | lists f64
  __shared__ float s_x2q[128];
  __shared__ float s_x2j[128];
  __shared__ float sbd[2][128];

  unsigned short* xj = (unsigned short*)uni;
  float* dch = (float*)uni;
  double* lst = (double*)uni;                // [128][20]

  const int b   = blockIdx.y;
  const int q0  = blockIdx.x * 128;
  const int jh  = blockIdx.z;
  const int tid = threadIdx.x;
  const int L   = tid & 63;
  const int w   = tid >> 6;
  const int lm  = L & 15;
  const int kg  = L >> 4;
  const int tq  = tid & 127;
  const int th  = tid >> 7;

  const float* Xb = X + (size_t)b * NPTS * ldx + coff;

  #pragma unroll
  for (int s=0;s<8;++s){
    int e = tid + s*256;
    int r = e >> 4, c4 = (e & 15) << 2;
    float4 v = *(const float4*)(Xb + (size_t)(q0+r)*ldx + c4);
    unsigned lo01, lo23;
    unsigned hi01 = bfsplit2(v.x, v.y, lo01);
    unsigned hi23 = bfsplit2(v.z, v.w, lo23);
    uint2 hp; hp.x = hi01; hp.y = hi23;
    uint2 lp; lp.x = lo01; lp.y = lo23;
    *(uint2*)&xq[r*72 + c4]        = hp;
    *(uint2*)&xq[9216 + r*72 + c4] = lp;
  }
  if (tid < 128) s_x2q[tid] = sqn[b*NPTS + q0 + tid];

  double bk[10];
  float g9 = INFINITY, pbd9 = INFINITY;
  #pragma unroll
  for (int u=0;u<10;++u) bk[u] = (double)INFINITY;

  for (int t = 0; t < 32; ++t) {
    const int j0 = jh*4096 + t*128;
    #pragma unroll
    for (int s=0;s<8;++s){
      int e = tid + s*256;
      int r = e >> 4, c4 = (e & 15) << 2;
      float4 v = *(const float4*)(Xb + (size_t)(j0+r)*ldx + c4);
      unsigned lo01, lo23;
      unsigned hi01 = bfsplit2(v.x, v.y, lo01);
      unsigned hi23 = bfsplit2(v.z, v.w, lo23);
      uint2 hp; hp.x = hi01; hp.y = hi23;
      uint2 lp; lp.x = lo01; lp.y = lo23;
      *(uint2*)&xj[r*72 + c4]        = hp;
      *(uint2*)&xj[9216 + r*72 + c4] = lp;
    }
    if (tid < 128) s_x2j[tid] = sqn[b*NPTS + j0 + tid];
    __syncthreads();   // A: staging done (covers xq at t=0; prev scan via last D)

    f32x4 acc[2][8];
    #pragma unroll
    for (int mt=0;mt<2;++mt)
      #pragma unroll
      for (int nt=0;nt<8;++nt) acc[mt][nt] = (f32x4){0.f,0.f,0.f,0.f};

    #pragma unroll
    for (int kc=0;kc<2;++kc){
      const int ko = kc*32 + kg*8;
      bf16x8s ah[2], al[2];
      #pragma unroll
      for (int mt=0;mt<2;++mt){
        int q = w*32 + mt*16 + lm;
        ah[mt] = *(const bf16x8s*)&xq[q*72 + ko];
        al[mt] = *(const bf16x8s*)&xq[9216 + q*72 + ko];
      }
      #pragma unroll
      for (int nt=0;nt<8;++nt){
        int n = nt*16 + lm;
        bf16x8s bh = *(const bf16x8s*)&xj[n*72 + ko];
        bf16x8s bl = *(const bf16x8s*)&xj[9216 + n*72 + ko];
        #pragma unroll
        for (int mt=0;mt<2;++mt){
          acc[mt][nt] = __builtin_amdgcn_mfma_f32_16x16x32_bf16(ah[mt], bh, acc[mt][nt], 0,0,0);
          acc[mt][nt] = __builtin_amdgcn_mfma_f32_16x16x32_bf16(ah[mt], bl, acc[mt][nt], 0,0,0);
          acc[mt][nt] = __builtin_amdgcn_mfma_f32_16x16x32_bf16(al[mt], bh, acc[mt][nt], 0,0,0);
        }
      }
    }
    __syncthreads();   // B: xj reads done; uni becomes dch[128][68]

    #pragma unroll
    for (int h=0; h<2; ++h) {
      // epilogue chunk h: cols h*64..h*64+63 of the 128-j tile
      #pragma unroll
      for (int mt=0;mt<2;++mt){
        #pragma unroll
        for (int ntl=0;ntl<4;++ntl){
          int nt = h*4 + ntl;
          f32x4 c = acc[mt][nt];
          int colc = ntl*16 + lm;
          float xj2 = s_x2j[h*64 + colc];
          #pragma unroll
          for (int r=0;r<4;++r){
            int qrow = w*32 + mt*16 + kg*4 + r;
            dch[qrow*68 + colc] = s_x2q[qrow] + xj2 - 2.0f*c[r];
          }
        }
      }
      __syncthreads();   // C: dch chunk written
      {
        const int jb0 = j0 + h*64 + th*32;
        #pragma unroll
        for (int c4=0;c4<8;++c4){
          float4 dv = *(const float4*)&dch[tq*68 + th*32 + c4*4];
          int jj = jb0 + c4*4;
          kinsd2(bk, g9, pbd9, dv.x, jj);
          kinsd2(bk, g9, pbd9, dv.y, jj+1);
          kinsd2(bk, g9, pbd9, dv.z, jj+2);
          kinsd2(bk, g9, pbd9, dv.w, jj+3);
        }
      }
      if (h == 1) sbd[th][tq] = (float)bk[9];
      __syncthreads();   // D: scan done (+ thresholds published at h=1)
      if (h == 1){
        pbd9 = sbd[1^th][tq];
        g9 = fminf((float)bk[9], pbd9);
      }
    }
  }

  // in-block merge of 2 per-thread lists per query (f64 key order == lex)
  #pragma unroll
  for (int u=0;u<10;++u) lst[tq*20 + th*10 + u] = bk[u];
  __syncthreads();
  if (tid < 128) {
    const double* row = &lst[tid*20];
    int ia=0, ib=0;
    size_t base = ((size_t)jh*(4*NPTS) + (size_t)b*NPTS + q0 + tid)*10;
    #pragma unroll
    for (int u=0;u<10;++u){
      double ka = row[ia], kb2 = row[10+ib];
      bool ta = ka < kb2;
      pk[base+u] = ta ? ka : kb2;
      ia += ta ? 1 : 0; ib += ta ? 0 : 1;
    }
  }
}

// ---------- KNN for conv1 (C=4, fp32 VALU GEMM, exact self-dist) ----------
__global__ __launch_bounds__(256, 2) void knn4_kernel(const float* __restrict__ X,
                                                      const float* __restrict__ sqn,
                                                      double* __restrict__ pk){
  __shared__ __align__(16) float xqT[4*132];
  __shared__ __align__(16) float uni[10752];   // xjT[4][132] | dch[128][68] | lists f64
  __shared__ float s_x2q[128];
  __shared__ float s_x2j[128];
  __shared__ float sbd[2][128];

  const int b   = blockIdx.y;
  const int q0  = blockIdx.x * 128;
  const int jh  = blockIdx.z;
  const int tid = threadIdx.x;
  const int tn  = tid & 15;
  const int tm  = tid >> 4;
  const int tq  = tid & 127;
  const int th  = tid >> 7;

  const float* Xb = X + (size_t)b * NPTS * 4;

  for (int i = tid; i < 128; i += 256) {
    float4 v = *(const float4*)(Xb + (size_t)(q0+i)*4);
    xqT[0*132+i] = v.x; xqT[1*132+i] = v.y; xqT[2*132+i] = v.z; xqT[3*132+i] = v.w;
  }
  if (tid < 128) s_x2q[tid] = sqn[b*NPTS + q0 + tid];

  const int sw  = ((tn>>2)&3) << 2;
  const int bp0 = (tn*8)     ^ sw;
  const int bp1 = (tn*8 + 4) ^ sw;

  double bk[10];
  float g9 = INFINITY, pbd9 = INFINITY;
  #pragma unroll
  for (int u=0;u<10;++u) bk[u] = (double)INFINITY;

  for (int t = 0; t < 32; ++t) {
    const int j0 = jh*4096 + t*128;
    for (int i = tid; i < 128; i += 256) {
      float4 v = *(const float4*)(Xb + (size_t)(j0+i)*4);
      int pj = i ^ (((i>>5)&3) << 2);
      uni[0*132+pj] = v.x; uni[1*132+pj] = v.y; uni[2*132+pj] = v.z; uni[3*132+pj] = v.w;
    }
    if (tid < 128) s_x2j[tid] = sqn[b*NPTS + j0 + tid];
    __syncthreads();   // A

    float acc[8][8];
    #pragma unroll
    for (int i=0;i<8;++i)
      #pragma unroll
      for (int j=0;j<8;++j) acc[i][j] = 0.f;

    #pragma unroll
    for (int kk=0; kk<4; ++kk) {
      float av[8], bv[8];
      *(float4*)&av[0] = *(const float4*)&xqT[kk*132 + tm*8];
      *(float4*)&av[4] = *(const float4*)&xqT[kk*132 + tm*8 + 4];
      *(float4*)&bv[0] = *(const float4*)&uni[kk*132 + bp0];
      *(float4*)&bv[4] = *(const float4*)&uni[kk*132 + bp1];
      #pragma unroll
      for (int i=0;i<8;++i)
        #pragma unroll
        for (int j=0;j<8;++j)
          acc[i][j] = fmaf(av[i], bv[j], acc[i][j]);
    }
    __syncthreads();   // B: gemm reads done; uni becomes dch[128][68]

    #pragma unroll
    for (int h=0; h<2; ++h) {
      // epilogue chunk h: thread (tn>>3)==h owns j = tn*8+u -> local col (tn&7)*8+u
      if ((tn>>3) == h) {
        #pragma unroll
        for (int qi=0; qi<8; ++qi) {
          const int row = tm*8 + qi;
          const float xq2 = s_x2q[row];
          float vv[8];
          #pragma unroll
          for (int u=0;u<8;++u)
            vv[u] = xq2 + s_x2j[tn*8 + u] - 2.f*acc[qi][u];
          *(float4*)&uni[row*68 + (tn&7)*8]     = make_float4(vv[0],vv[1],vv[2],vv[3]);
          *(float4*)&uni[row*68 + (tn&7)*8 + 4] = make_float4(vv[4],vv[5],vv[6],vv[7]);
        }
      }
      __syncthreads();   // C
      {
        const int jb0 = j0 + h*64 + th*32;
        #pragma unroll
        for (int c4=0;c4<8;++c4){
          float4 dv = *(const float4*)&uni[tq*68 + th*32 + c4*4];
          int jj = jb0 + c4*4;
          kinsd2(bk, g9, pbd9, dv.x, jj);
          kinsd2(bk, g9, pbd9, dv.y, jj+1);
          kinsd2(bk, g9, pbd9, dv.z, jj+2);
          kinsd2(bk, g9, pbd9, dv.w, jj+3);
        }
      }
      if (h == 1) sbd[th][tq] = (float)bk[9];
      __syncthreads();   // D
      if (h == 1){
        pbd9 = sbd[1^th][tq];
        g9 = fminf((float)bk[9], pbd9);
      }
    }
  }

  double* lst = (double*)uni;    // [128][20]
  #pragma unroll
  for (int u=0;u<10;++u) lst[tq*20 + th*10 + u] = bk[u];
  __syncthreads();
  if (tid < 128) {
    const double* row = &lst[tid*20];
    int ia=0, ib=0;
    size_t base = ((size_t)jh*(4*NPTS) + (size_t)b*NPTS + q0 + tid)*10;
    #pragma unroll
    for (int u=0;u<10;++u){
      double ka = row[ia], kb2 = row[10+ib];
      bool ta = ka < kb2;
      pk[base+u] = ta ? ka : kb2;
      ia += ta ? 1 : 0; ib += ta ? 0 : 1;
    }
  }
}

// ---------- merge the 2 j-half partial f64-key lists -> final idx ----------
__global__ __launch_bounds__(256) void knnmerge_kernel(const double* __restrict__ pk,
                                                       int* __restrict__ idxout){
  int p = blockIdx.x*256 + threadIdx.x;   // 0..32767
  const double* A = pk + (size_t)p*10;
  const double* B = pk + (size_t)(4*NPTS)*10 + (size_t)p*10;
  int ia=0, ib=0;
  int* op = idxout + (size_t)p*10;
  #pragma unroll
  for (int u=0;u<10;++u){
    double ka = A[ia], kb = B[ib];
    bool t = ka < kb;
    op[u] = (int)(__double_as_longlong(t ? ka : kb) & 8191LL);
    ia += t ? 1 : 0; ib += t ? 0 : 1;
  }
}

// ---------- prep U/D for 64-ch edge conv ----------
__global__ __launch_bounds__(256) void prepUD64_kernel(const float* __restrict__ XC, int cin,
                                                       const float* __restrict__ W,
                                                       float* __restrict__ U,
                                                       float* __restrict__ D){
  int p = blockIdx.x*256 + threadIdx.x;
  float x[64];
  {
    const float4* xr = (const float4*)(XC + (size_t)p*192 + cin);
    #pragma unroll
    for (int c4=0;c4<16;++c4){
      float4 v = xr[c4];
      x[c4*4]=v.x; x[c4*4+1]=v.y; x[c4*4+2]=v.z; x[c4*4+3]=v.w;
    }
  }
  const float4* W4 = (const float4*)W;
  float4 z[16];
  #pragma unroll
  for (int o=0;o<16;++o) z[o] = make_float4(0,0,0,0);
  #pragma unroll
  for (int c=0;c<64;++c) {
    const float xc = x[c];
    #pragma unroll
    for (int o=0;o<16;++o) z[o] = f4fma(xc, W4[c*16+o], z[o]);
  }
  float4* up = (float4*)(U + (size_t)p*64);
  #pragma unroll
  for (int o=0;o<16;++o) up[o] = z[o];
  #pragma unroll
  for (int o=0;o<16;++o) z[o] = make_float4(0,0,0,0);
  #pragma unroll
  for (int c=0;c<64;++c) {
    const float xc = x[c];
    #pragma unroll
    for (int o=0;o<16;++o) {
      float4 wt = W4[c*16+o], wb = W4[(64+c)*16+o];
      float4 wd = make_float4(wb.x-wt.x, wb.y-wt.y, wb.z-wt.z, wb.w-wt.w);
      z[o] = f4fma(xc, wd, z[o]);
    }
  }
  float4* dp = (float4*)(D + (size_t)p*64);
  #pragma unroll
  for (int o=0;o<16;++o) dp[o] = z[o];
}

// ---------- prep U/D for conv1 ----------
__global__ __launch_bounds__(256) void prepUD12_kernel(const float* __restrict__ T,
                                                       const float* __restrict__ W1,
                                                       float* __restrict__ U,
                                                       float* __restrict__ D){
  int p = blockIdx.x*256 + threadIdx.x;
  float t[3] = {T[p*3+0], T[p*3+1], T[p*3+2]};
  const float4* W = (const float4*)W1;
  float4 u[16], q[16];
  #pragma unroll
  for (int o=0;o<16;++o){ u[o]=make_float4(0,0,0,0); q[o]=make_float4(0,0,0,0); }
  #pragma unroll
  for (int c=0;c<3;++c){
    const float tc = t[c];
    #pragma unroll
    for (int o=0;o<16;++o){
      float4 ws  = W[c*16+o],     ws2 = W[(c+3)*16+o];
      float4 wq  = W[(c+6)*16+o], wq2 = W[(c+9)*16+o];
      u[o] = f4fma(tc, make_float4(ws.x+ws2.x, ws.y+ws2.y, ws.z+ws2.z, ws.w+ws2.w), u[o]);
      q[o] = f4fma(tc, make_float4(wq.x+wq2.x, wq.y+wq2.y, wq.z+wq2.z, wq.w+wq2.w), q[o]);
    }
  }
  float4* up = (float4*)(U + (size_t)p*64);
  float4* dp = (float4*)(D + (size_t)p*64);
  #pragma unroll
  for (int o=0;o<16;++o){
    up[o] = u[o];
    dp[o] = make_float4(q[o].x-u[o].x, q[o].y-u[o].y, q[o].z-u[o].z, q[o].w-u[o].w);
  }
}

// ---------- two-layer edge conv, wave-per-point + fused sqnorm of the output row ----------
__global__ __launch_bounds__(256) void edge2w_kernel(const float* __restrict__ U,
                                                     const float* __restrict__ Dp,
                                                     const int* __restrict__ idx,
                                                     const float* __restrict__ Wb,
                                                     const float* __restrict__ PA, int paa, int pab,
                                                     float* __restrict__ out, int coff,
                                                     float* __restrict__ sqnout){
  __shared__ __align__(16) float sh[4][10][68];
  const int tid = threadIdx.x;
  const int w = tid >> 6, o = tid & 63;
  const int p = blockIdx.x*4 + w, b = p >> 13;
  const float aa = PA[paa], ab = PA[pab];

  float wreg[64];
  #pragma unroll
  for (int c=0;c<64;++c) wreg[c] = Wb[c*64 + o];

  const float dc = Dp[(size_t)p*64 + o];

  #pragma unroll
  for (int k=0;k<10;++k){
    int nb = idx[p*10 + k];
    float u = U[((size_t)(b<<13)+nb)*64 + o];
    sh[w][k][o] = preluf(u + dc, aa);
  }
  __syncthreads();

  float mx = -INFINITY;
  #pragma unroll 2
  for (int k=0;k<10;++k){
    float a0=0.f,a1=0.f,a2=0.f,a3=0.f;
    #pragma unroll
    for (int c4=0;c4<16;++c4){
      float4 hv = *(const float4*)&sh[w][k][c4*4];
      a0 = fmaf(hv.x, wreg[c4*4+0], a0);
      a1 = fmaf(hv.y, wreg[c4*4+1], a1);
      a2 = fmaf(hv.z, wreg[c4*4+2], a2);
      a3 = fmaf(hv.w, wreg[c4*4+3], a3);
    }
    float z = (a0+a1)+(a2+a3);
    mx = fmaxf(mx, preluf(z, ab));
  }
  out[(size_t)p*192 + coff + o] = mx;
  // fused sqnorm of this 64-col output row (feeds the next conv's KNN)
  float sq = mx*mx;
  #pragma unroll
  for (int off=1; off<64; off<<=1) sq += __shfl_xor(sq, off);
  if (o == 0) sqnout[p] = sq;
}

// ---------- single-layer edge conv (conv3), wave-per-point ----------
__global__ __launch_bounds__(256) void edge1w_kernel(const float* __restrict__ U,
                                                     const float* __restrict__ Dp,
                                                     const int* __restrict__ idx,
                                                     const float* __restrict__ PA, int paa,
                                                     float* __restrict__ out, int coff){
  const int tid = threadIdx.x;
  const int w = tid >> 6, o = tid & 63;
  const int p = blockIdx.x*4 + w, b = p >> 13;
  const float aa = PA[paa];
  const float dc = Dp[(size_t)p*64 + o];
  float mx = -INFINITY;
  #pragma unroll
  for (int k=0;k<10;++k){
    int nb = idx[p*10 + k];
    float u = U[((size_t)(b<<13)+nb)*64 + o];
    mx = fmaxf(mx, preluf(u + dc, aa));
  }
  out[(size_t)p*192 + coff + o] = mx;
}

// ---------- fused weight prep: all four head weights -> hi/lo transposed ----------
__global__ __launch_bounds__(256) void prepWall_kernel(const float* __restrict__ W6,
                                                       const float* __restrict__ W7,
                                                       const float* __restrict__ W8,
                                                       const float* __restrict__ W9,
                                                       unsigned short* __restrict__ Wh6, unsigned short* __restrict__ Wl6,
                                                       unsigned short* __restrict__ Wh7, unsigned short* __restrict__ Wl7,
                                                       unsigned short* __restrict__ Wh8, unsigned short* __restrict__ Wl8,
                                                       unsigned short* __restrict__ Wh9, unsigned short* __restrict__ Wl9){
  int bb = blockIdx.x;
  const float* W; unsigned short *Wh, *Wl; int K, N, k;
  if (bb < 192)      { W=W6; Wh=Wh6; Wl=Wl6; K=192; N=1024; k=bb; }
  else if (bb < 384) { W=W7; Wh=Wh7; Wl=Wl7; K=192; N=256;  k=bb-192; }
  else if (bb < 640) { W=W8; Wh=Wh8; Wl=Wl8; K=256; N=256;  k=bb-384; }
  else               { W=W9; Wh=Wh9; Wl=Wl9; K=256; N=128;  k=bb-640; }
  for (int n = threadIdx.x; n < N; n += 256){
    float v = W[(size_t)k*N + n];
    unsigned ua = __float_as_uint(v);
    unsigned h = (ua + 0x7FFFu + ((ua>>16)&1u)) & 0xFFFF0000u;
    float r = v - __uint_as_float(h);
    unsigned ub = __float_as_uint(r);
    unsigned l = (ub + 0x7FFFu + ((ub>>16)&1u)) >> 16;
    Wh[(size_t)n*K + k] = (unsigned short)(h >> 16);
    Wl[(size_t)n*K + k] = (unsigned short)l;
  }
}

// ---------- MFMA bf16 hi/lo GEMM: C = prelu(A@W [+bias]); EPI2: colmax partials ----------
template<int EPI>
__global__ __launch_bounds__(256, 2) void mgemm_kernel(const float* __restrict__ A, int lda,
                                                       const unsigned short* __restrict__ WhT,
                                                       const unsigned short* __restrict__ WlT,
                                                       int K,
                                                       float* __restrict__ C, int ldc,
                                                       const float* __restrict__ bias,
                                                       const float* __restrict__ PA, int pidx,
                                                       int Ntot){
  __shared__ __align__(16) unsigned char smem[73728];
  unsigned short* sa = (unsigned short*)smem;
  unsigned short* sb = (unsigned short*)(smem + 36864);
  float* cst = (float*)smem;

  const int tid = threadIdx.x;
  const int m0 = blockIdx.x*128, n0 = blockIdx.y*128;
  const int L = tid & 63, w = tid >> 6;
  const int lm = L & 15, kg = L >> 4;

  f32x4 acc[2][8];
  #pragma unroll
  for (int mt=0;mt<2;++mt)
    #pragma unroll
    for (int nt=0;nt<8;++nt) acc[mt][nt] = (f32x4){0.f,0.f,0.f,0.f};

  for (int c0 = 0; c0 < K; c0 += 64) {
    __syncthreads();
    #pragma unroll
    for (int s=0;s<8;++s){
      int e = tid + s*256;
      int r = e >> 4, kq = (e & 15) << 2;
      float4 v = *(const float4*)(A + (size_t)(m0+r)*lda + c0 + kq);
      unsigned lo01, lo23;
      unsigned hi01 = bfsplit2(v.x, v.y, lo01);
      unsigned hi23 = bfsplit2(v.z, v.w, lo23);
      uint2 hp; hp.x = hi01; hp.y = hi23;
      uint2 lp; lp.x = lo01; lp.y = lo23;
      *(uint2*)&sa[r*72 + kq]        = hp;
      *(uint2*)&sa[9216 + r*72 + kq] = lp;
    }
    #pragma unroll
    for (int s=0;s<4;++s){
      int e = tid + s*256;
      int col = e >> 3, ko = (e & 7) << 3;
      *(uint4*)&sb[col*72 + ko]        = *(const uint4*)&WhT[(size_t)(n0+col)*K + c0 + ko];
      *(uint4*)&sb[9216 + col*72 + ko] = *(const uint4*)&WlT[(size_t)(n0+col)*K + c0 + ko];
    }
    __syncthreads();

    #pragma unroll
    for (int kc=0;kc<2;++kc){
      const int ko = kc*32 + kg*8;
      bf16x8s ah[2], al[2];
      #pragma unroll
      for (int mt=0;mt<2;++mt){
        int q = w*32 + mt*16 + lm;
        ah[mt] = *(const bf16x8s*)&sa[q*72 + ko];
        al[mt] = *(const bf16x8s*)&sa[9216 + q*72 + ko];
      }
      #pragma unroll
      for (int nt=0;nt<8;++nt){
        int n = nt*16 + lm;
        bf16x8s bh = *(const bf16x8s*)&sb[n*72 + ko];
        bf16x8s bl = *(const bf16x8s*)&sb[9216 + n*72 + ko];
        #pragma unroll
        for (int mt=0;mt<2;++mt){
          acc[mt][nt] = __builtin_amdgcn_mfma_f32_16x16x32_bf16(ah[mt], bh, acc[mt][nt], 0,0,0);
          acc[mt][nt] = __builtin_amdgcn_mfma_f32_16x16x32_bf16(ah[mt], bl, acc[mt][nt], 0,0,0);
          acc[mt][nt] = __builtin_amdgcn_mfma_f32_16x16x32_bf16(al[mt], bh, acc[mt][nt], 0,0,0);
        }
      }
    }
  }
  __syncthreads();

  const float a = PA[pidx];
  if (EPI == 2) {
    #pragma unroll
    for (int nt=0;nt<8;++nt){
      f32x4 c0v = acc[0][nt], c1v = acc[1][nt];
      float m = -INFINITY;
      #pragma unroll
      for (int r=0;r<4;++r){ m = fmaxf(m, preluf(c0v[r], a)); m = fmaxf(m, preluf(c1v[r], a)); }
      m = fmaxf(m, __shfl_xor(m, 16));
      m = fmaxf(m, __shfl_xor(m, 32));
      if (kg == 0) cst[w*128 + nt*16 + lm] = m;
    }
    __syncthreads();
    if (tid < 128){
      float m = fmaxf(fmaxf(cst[tid], cst[128+tid]), fmaxf(cst[256+tid], cst[384+tid]));
      C[(size_t)blockIdx.x*Ntot + n0 + tid] = m;
    }
  } else {
    float bc[8];
    if (EPI == 1){
      int bb = m0 >> 13;
      #pragma unroll
      for (int nt=0;nt<8;++nt) bc[nt] = bias[bb*256 + n0 + nt*16 + lm];
    }
    #pragma unroll
    for (int mt=0;mt<2;++mt){
      #pragma unroll
      for (int nt=0;nt<8;++nt){
        f32x4 c = acc[mt][nt];
        int col = nt*16 + lm;
        #pragma unroll
        for (int r=0;r<4;++r){
          int row = w*32 + mt*16 + kg*4 + r;
          float v = c[r] + (EPI==1 ? bc[nt] : 0.f);
          cst[row*132 + col] = preluf(v, a);
        }
      }
    }
    __syncthreads();
    const int tm = tid & 15, tn = tid >> 4;
    #pragma unroll
    for (int i=0;i<8;++i){
      int row = tm*8 + i;
      float4 v0 = *(const float4*)&cst[row*132 + tn*8];
      float4 v1 = *(const float4*)&cst[row*132 + tn*8 + 4];
      float* cp = C + (size_t)(m0 + row)*ldc + n0 + tn*8;
      *(float4*)cp     = v0;
      *(float4*)(cp+4) = v1;
    }
  }
}

__global__ __launch_bounds__(256) void reduce_pmax(const float* __restrict__ pmax,
                                                   float* __restrict__ x5m){
  int t = blockIdx.x*256 + threadIdx.x;
  if (t < 4096) {
    int b = t >> 10, o = t & 1023;
    float m = -INFINITY;
    for (int mt=0; mt<64; ++mt) m = fmaxf(m, pmax[((size_t)(b*64+mt))*1024 + o]);
    x5m[t] = m;
  }
}

__global__ __launch_bounds__(256) void bias7_kernel(const float* __restrict__ x5m,
                                                    const float* __restrict__ W7,
                                                    float* __restrict__ b7){
  int b = blockIdx.x; int o = threadIdx.x;
  float s = 0.f;
  for (int j=0;j<1024;++j) s = fmaf(x5m[b*1024+j], W7[(size_t)(192+j)*256 + o], s);
  b7[b*256+o] = s;
}

__global__ __launch_bounds__(256) void final10_kernel(const float* __restrict__ y3,
                                                      const float* __restrict__ W10,
                                                      const float* __restrict__ PA,
                                                      float* __restrict__ out){
  int p = blockIdx.x*256 + threadIdx.x;
  const float4* r = (const float4*)(y3 + (size_t)p*128);
  float s0=0.f, s1=0.f;
  #pragma unroll
  for (int c4=0;c4<32;++c4){
    float4 v = r[c4];
    s0 = fmaf(v.x, W10[(c4*4+0)*2+0], s0); s1 = fmaf(v.x, W10[(c4*4+0)*2+1], s1);
    s0 = fmaf(v.y, W10[(c4*4+1)*2+0], s0); s1 = fmaf(v.y, W10[(c4*4+1)*2+1], s1);
    s0 = fmaf(v.z, W10[(c4*4+2)*2+0], s0); s1 = fmaf(v.z, W10[(c4*4+2)*2+1], s1);
    s0 = fmaf(v.w, W10[(c4*4+3)*2+0], s0); s1 = fmaf(v.w, W10[(c4*4+3)*2+1], s1);
  }
  float a = PA[9];
  out[p*2+0] = s0>=0.f? s0 : a*s0;
  out[p*2+1] = s1>=0.f? s1 : a*s1;
}

extern "C" void kernel_launch(void* const* d_in, const int* in_sizes, int n_in,
                              void* d_out, int out_size, void* d_ws, size_t ws_size,
                              hipStream_t stream) {
  const float* T   = (const float*)d_in[0];
  const float* W1  = (const float*)d_in[1];
  const float* W2  = (const float*)d_in[2];
  const float* W3  = (const float*)d_in[3];
  const float* W4  = (const float*)d_in[4];
  const float* W5  = (const float*)d_in[5];
  const float* W6  = (const float*)d_in[6];
  const float* W7  = (const float*)d_in[7];
  const float* W8  = (const float*)d_in[8];
  const float* W9  = (const float*)d_in[9];
  const float* W10 = (const float*)d_in[10];
  const float* PA  = (const float*)d_in[11];

  float* ws   = (float*)d_ws;
  float* x0   = ws + 0;                // 131072
  float* sqn0 = ws + 131072;           // 32768
  float* sqn1 = ws + 163840;           // 32768
  float* sqn2 = ws + 196608;           // 32768
  int*   idx0 = (int*)(ws + 229376);   // 327680
  int*   idx1 = (int*)(ws + 557056);   // 327680
  int*   idx2 = (int*)(ws + 884736);   // 327680
  float* xcat = ws + 1212416;          // 6291456  [B,N,192]
  float* pmax = ws + 7503872;          // 262144
  float* x5m  = ws + 7766016;          // 4096
  float* b7   = ws + 7770112;          // 1024
  float* y1   = ws + 7771136;          // 8388608  (aliased: U / knn f64 partials)
  float* y2   = ws + 16159744;         // 8388608  (aliased: D)
  float* y3   = xcat;
  float* U    = y1;
  float* D    = y2;
  double* pk  = (double*)y1;           // [2][32768][10] f64 keys = 5.24 MB

  // split/transposed weights: reuse idx region (dead after edge1w)
  unsigned short* wsc = (unsigned short*)(ws + 229376);
  unsigned short* Wh6 = wsc;
  unsigned short* Wl6 = wsc + 196608;
  unsigned short* Wh7 = wsc + 393216;
  unsigned short* Wl7 = wsc + 442368;
  unsigned short* Wh8 = wsc + 491520;
  unsigned short* Wl8 = wsc + 557056;
  unsigned short* Wh9 = wsc + 622592;
  unsigned short* Wl9 = wsc + 655360;

  // conv1
  prep0_kernel<<<128, 256, 0, stream>>>(T, x0, sqn0);
  knn4_kernel<<<dim3(64,4,2), 256, 0, stream>>>(x0, sqn0, pk);
  knnmerge_kernel<<<128, 256, 0, stream>>>(pk, idx0);
  prepUD12_kernel<<<128, 256, 0, stream>>>(T, W1, U, D);
  edge2w_kernel<<<8192, 256, 0, stream>>>(U, D, idx0, W2, PA, 0, 1, xcat, 0, sqn1);

  // conv2
  knn64_kernel<<<dim3(64,4,2), 256, 0, stream>>>(xcat, 192, 0, sqn1, pk);
  knnmerge_kernel<<<128, 256, 0, stream>>>(pk, idx1);
  prepUD64_kernel<<<128, 256, 0, stream>>>(xcat, 0, W3, U, D);
  edge2w_kernel<<<8192, 256, 0, stream>>>(U, D, idx1, W4, PA, 2, 3, xcat, 64, sqn2);

  // conv3
  knn64_kernel<<<dim3(64,4,2), 256, 0, stream>>>(xcat, 192, 64, sqn2, pk);
  knnmerge_kernel<<<128, 256, 0, stream>>>(pk, idx2);
  prepUD64_kernel<<<128, 256, 0, stream>>>(xcat, 64, W5, U, D);
  edge1w_kernel<<<8192, 256, 0, stream>>>(U, D, idx2, PA, 4, xcat, 128);

  // head weights -> bf16 hi/lo transposed (one fused launch)
  prepWall_kernel<<<896, 256, 0, stream>>>(W6, W7, W8, W9,
                                           Wh6, Wl6, Wh7, Wl7, Wh8, Wl8, Wh9, Wl9);

  // head
  mgemm_kernel<2><<<dim3(256,8), 256, 0, stream>>>(xcat, 192, Wh6, Wl6, 192, pmax, 0, nullptr, PA, 5, 1024);
  reduce_pmax<<<16, 256, 0, stream>>>(pmax, x5m);
  bias7_kernel<<<4, 256, 0, stream>>>(x5m, W7, b7);
  mgemm_kernel<1><<<dim3(256,2), 256, 0, stream>>>(xcat, 192, Wh7, Wl7, 192, y1, 256, b7, PA, 6, 0);
  mgemm_kernel<0><<<dim3(256,2), 256, 0, stream>>>(y1, 256, Wh8, Wl8, 256, y2, 256, nullptr, PA, 7, 0);
  mgemm_kernel<0><<<dim3(256,1), 256, 0, stream>>>(y2, 256, Wh9, Wl9, 256, y3, 128, nullptr, PA, 8, 0);
  final10_kernel<<<128, 256, 0, stream>>>(y3, W10, PA, (float*)d_out);
}